// Round 3
// baseline (500.527 us; speedup 1.0000x reference)
//
#include <hip/hip_runtime.h>
#include <hip/hip_bf16.h>

// ---------------------------------------------------------------------------
// MMD loss:  mmd = Sxx_up*2/(n(n-1)) + Syy_up*2/(m(m-1)) - 2*Sxy/(n*m)
// k(a,b) = exp(-|a-b|^2/128),  N = M = 8192, D = 64.
//
// exp2 domain: k = exp2( (a.b)*C2L + nsa + nsb ),  nsa = -|a|^2*log2e/128
// (precomputed, negated).  bf16 MFMA 16x16x32, K=64 = 2 chained MFMAs.
//
// Round-3 structure (fixing r2's occupancy collapse, VGPR 124 -> <=64):
//  - block tile 128(i) x 128(j); 4 waves, each 32(i) x 128(j)
//  - B tile (16 KB) staged to LDS with 144-B padded rows (2 lanes/bank = free)
//  - A fragments (16 VGPR) + neg-norms (8 VGPR) persist in registers
//  - __launch_bounds__(256,8): 8 waves/SIMD; LDS 19 KB -> 8 blocks/CU
//  - per-block double atomicAdd + ticket; last block writes clamped output
// ---------------------------------------------------------------------------

using short8 = __attribute__((ext_vector_type(8))) short;  // 8 bf16 (4 VGPRs)
using f32x4  = __attribute__((ext_vector_type(4))) float;  // 4 fp32

#define NROWS 8192
#define DDIM  64
#define LOG2E 1.4426950408889634f
#define TOTAL_BLOCKS (64 * 64 * 3)
#define LDS_ROW 72   // 64 elems + 8 pad (144 B rows: read/write = 2-way = free)

// ---------------------------------------------------------------------------
// Prep: normalize X, cast X/Y to bf16, norms pre-scaled by -log2e/128.
// 16 threads per row, float4 per thread.  Block 0 also zeroes the accumulator.
// ---------------------------------------------------------------------------
__global__ __launch_bounds__(256) void mmd_prep(
    const float* __restrict__ z_seq, const float* __restrict__ pmean,
    const float* __restrict__ pstd, const float* __restrict__ z_prior,
    unsigned short* __restrict__ Xb, unsigned short* __restrict__ Yb,
    float* __restrict__ sxx, float* __restrict__ syy,
    double* __restrict__ accum)
{
    if (blockIdx.x == 0 && threadIdx.x == 0) {
        accum[0] = 0.0;
        *reinterpret_cast<unsigned*>(accum + 1) = 0u;
    }
    const int gt  = blockIdx.x * 256 + threadIdx.x;  // 0..262143
    const int row = gt >> 4;                         // 0..16383
    const int sub = gt & 15;                         // 4 floats each

    float4 v;
    unsigned short* dst;
    float* sdst;
    int r;
    if (row < NROWS) {
        r = row;
        v = *reinterpret_cast<const float4*>(z_seq + (size_t)r * DDIM + sub * 4);
        float4 m = *reinterpret_cast<const float4*>(pmean + sub * 4);
        float4 s = *reinterpret_cast<const float4*>(pstd + sub * 4);
        v.x = (v.x - m.x) / s.x;
        v.y = (v.y - m.y) / s.y;
        v.z = (v.z - m.z) / s.z;
        v.w = (v.w - m.w) / s.w;
        dst = Xb; sdst = sxx;
    } else {
        r = row - NROWS;
        v = *reinterpret_cast<const float4*>(z_prior + (size_t)r * DDIM + sub * 4);
        dst = Yb; sdst = syy;
    }
    __hip_bfloat16 h0 = __float2bfloat16(v.x);
    __hip_bfloat16 h1 = __float2bfloat16(v.y);
    __hip_bfloat16 h2 = __float2bfloat16(v.z);
    __hip_bfloat16 h3 = __float2bfloat16(v.w);
    ushort4 pk;
    pk.x = *reinterpret_cast<unsigned short*>(&h0);
    pk.y = *reinterpret_cast<unsigned short*>(&h1);
    pk.z = *reinterpret_cast<unsigned short*>(&h2);
    pk.w = *reinterpret_cast<unsigned short*>(&h3);
    *reinterpret_cast<ushort4*>(dst + (size_t)r * DDIM + sub * 4) = pk;

    float b0 = __bfloat162float(h0), b1 = __bfloat162float(h1);
    float b2 = __bfloat162float(h2), b3 = __bfloat162float(h3);
    float sq = (b0 * b0 + b1 * b1) + (b2 * b2 + b3 * b3);
#pragma unroll
    for (int off = 1; off <= 8; off <<= 1) sq += __shfl_xor(sq, off, 64);
    if (sub == 0) sdst[r] = -sq * (LOG2E / 128.0f);
}

// ---------------------------------------------------------------------------
// Main: grid (64 bj, 64 bi, 3 modes).  Block tile 128 x 128.
// ---------------------------------------------------------------------------
__global__ __launch_bounds__(256, 8) void mmd_main(
    const unsigned short* __restrict__ Xb, const unsigned short* __restrict__ Yb,
    const float* __restrict__ sxx, const float* __restrict__ syy,
    double* __restrict__ accum, float* __restrict__ out)
{
    __shared__ unsigned short Bsh[128 * LDS_ROW];   // 18 KB, padded rows
    __shared__ float sy_sh[128];
    __shared__ float ws4[4];

    const int bj = blockIdx.x, bi = blockIdx.y, mode = blockIdx.z;
    const unsigned short* A;
    const unsigned short* Bp;
    const float* sa;
    const float* sb;
    if (mode == 0)      { A = Xb; Bp = Xb; sa = sxx; sb = sxx; }
    else if (mode == 1) { A = Yb; Bp = Yb; sa = syy; sb = syy; }
    else                { A = Xb; Bp = Yb; sa = sxx; sb = syy; }
    const bool sym = (mode < 2);

    const int t = threadIdx.x;
    const int lane = t & 63, w = t >> 6, quad = lane >> 4, l15 = lane & 15;
    const int iBlock = bi * 128, jBlock = bj * 128;

    float s0 = 0.f, s1 = 0.f, s2 = 0.f, s3 = 0.f;
    constexpr float C2L = LOG2E / 64.0f;

    const bool dead = sym && (bi > bj);   // strictly below diagonal
    if (!dead) {
        // ---- stage B tile + j-norms into LDS (coalesced 16B chunks) ----
#pragma unroll
        for (int i = 0; i < 4; ++i) {
            const int g = i * 256 + t;           // chunk id, 8 chunks/row
            const int row = g >> 3, c = g & 7;
            short8 ch = *reinterpret_cast<const short8*>(
                Bp + (size_t)(jBlock + row) * DDIM + c * 8);
            *reinterpret_cast<short8*>(Bsh + row * LDS_ROW + c * 8) = ch;
        }
        if (t < 128) sy_sh[t] = sb[jBlock + t];
        __syncthreads();

        // ---- persistent A fragments (32 rows per wave) ----
        const int i0 = iBlock + 32 * w;
        const unsigned short* Ap = A + (size_t)(i0 + l15) * DDIM + quad * 8;
        short8 af[2][2];
        f32x4  nx[2];
#pragma unroll
        for (int mt = 0; mt < 2; ++mt) {
            af[mt][0] = *reinterpret_cast<const short8*>(Ap + mt * 16 * DDIM);
            af[mt][1] = *reinterpret_cast<const short8*>(Ap + mt * 16 * DDIM + 32);
            nx[mt]    = *reinterpret_cast<const f32x4*>(sa + i0 + mt * 16 + quad * 4);
        }
        const unsigned short* Bl = Bsh + l15 * LDS_ROW + quad * 8;

        if (!sym || bi < bj) {
            // ---------------- clean path: all 8 strips, branch-free --------
#pragma unroll
            for (int nt = 0; nt < 8; ++nt) {
                short8 b0 = *reinterpret_cast<const short8*>(Bl + nt * 16 * LDS_ROW);
                short8 b1 = *reinterpret_cast<const short8*>(Bl + nt * 16 * LDS_ROW + 32);
                const float ny = sy_sh[nt * 16 + l15];
#pragma unroll
                for (int mt = 0; mt < 2; ++mt) {
                    f32x4 a0 = {0.f, 0.f, 0.f, 0.f};
                    a0 = __builtin_amdgcn_mfma_f32_16x16x32_bf16(af[mt][0], b0, a0, 0, 0, 0);
                    f32x4 acc = __builtin_amdgcn_mfma_f32_16x16x32_bf16(af[mt][1], b1, a0, 0, 0, 0);
                    s0 += __builtin_amdgcn_exp2f(fmaf(acc[0], C2L, nx[mt][0] + ny));
                    s1 += __builtin_amdgcn_exp2f(fmaf(acc[1], C2L, nx[mt][1] + ny));
                    s2 += __builtin_amdgcn_exp2f(fmaf(acc[2], C2L, nx[mt][2] + ny));
                    s3 += __builtin_amdgcn_exp2f(fmaf(acc[3], C2L, nx[mt][3] + ny));
                }
            }
        } else {
            // ---------------- diagonal-straddling block (bi == bj) --------
#pragma unroll
            for (int nt = 0; nt < 8; ++nt) {
                const int jtA = jBlock + nt * 16;
                if (jtA < i0) continue;            // both tiles below diagonal
                short8 b0 = *reinterpret_cast<const short8*>(Bl + nt * 16 * LDS_ROW);
                short8 b1 = *reinterpret_cast<const short8*>(Bl + nt * 16 * LDS_ROW + 32);
                const float ny = sy_sh[nt * 16 + l15];
#pragma unroll
                for (int mt = 0; mt < 2; ++mt) {
                    const int itA = i0 + mt * 16;
                    if (jtA < itA) continue;       // tile strictly below diag
                    f32x4 a0 = {0.f, 0.f, 0.f, 0.f};
                    a0 = __builtin_amdgcn_mfma_f32_16x16x32_bf16(af[mt][0], b0, a0, 0, 0, 0);
                    f32x4 acc = __builtin_amdgcn_mfma_f32_16x16x32_bf16(af[mt][1], b1, a0, 0, 0, 0);
                    if (jtA == itA) {
                        float v0 = __builtin_amdgcn_exp2f(fmaf(acc[0], C2L, nx[mt][0] + ny));
                        float v1 = __builtin_amdgcn_exp2f(fmaf(acc[1], C2L, nx[mt][1] + ny));
                        float v2 = __builtin_amdgcn_exp2f(fmaf(acc[2], C2L, nx[mt][2] + ny));
                        float v3 = __builtin_amdgcn_exp2f(fmaf(acc[3], C2L, nx[mt][3] + ny));
                        s0 += (l15 > quad * 4 + 0) ? v0 : 0.f;  // strictly j>i
                        s1 += (l15 > quad * 4 + 1) ? v1 : 0.f;
                        s2 += (l15 > quad * 4 + 2) ? v2 : 0.f;
                        s3 += (l15 > quad * 4 + 3) ? v3 : 0.f;
                    } else {
                        s0 += __builtin_amdgcn_exp2f(fmaf(acc[0], C2L, nx[mt][0] + ny));
                        s1 += __builtin_amdgcn_exp2f(fmaf(acc[1], C2L, nx[mt][1] + ny));
                        s2 += __builtin_amdgcn_exp2f(fmaf(acc[2], C2L, nx[mt][2] + ny));
                        s3 += __builtin_amdgcn_exp2f(fmaf(acc[3], C2L, nx[mt][3] + ny));
                    }
                }
            }
        }
    }

    // ---- block reduce + global accumulate (all blocks, incl. dead) ----
    float wsum = (s0 + s1) + (s2 + s3);
#pragma unroll
    for (int off = 32; off; off >>= 1) wsum += __shfl_xor(wsum, off, 64);
    if (lane == 0) ws4[w] = wsum;
    __syncthreads();
    if (t == 0) {
        const double coef = sym ? (2.0 / (8192.0 * 8191.0))
                                : (-2.0 / (8192.0 * 8192.0));
        atomicAdd(accum, (double)(ws4[0] + ws4[1] + ws4[2] + ws4[3]) * coef);
        __threadfence();
        unsigned tk = atomicAdd(reinterpret_cast<unsigned*>(accum + 1), 1u);
        if (tk == TOTAL_BLOCKS - 1) {
            double vsum = atomicAdd(accum, 0.0);   // device-scope read
            out[0] = (float)(vsum > 0.0 ? vsum : 0.0);
        }
    }
}

// ---------------------------------------------------------------------------
extern "C" void kernel_launch(void* const* d_in, const int* in_sizes, int n_in,
                              void* d_out, int out_size, void* d_ws, size_t ws_size,
                              hipStream_t stream) {
    const float* z_seq   = (const float*)d_in[0];   // [16,512,64]
    const float* pmean   = (const float*)d_in[1];   // [64]
    const float* pstd    = (const float*)d_in[2];   // [64]
    const float* z_prior = (const float*)d_in[3];   // [8192,64]
    float* out = (float*)d_out;

    char* ws = (char*)d_ws;
    unsigned short* Xb = (unsigned short*)(ws);                    // 1 MB
    unsigned short* Yb = (unsigned short*)(ws + (1u << 20));       // 1 MB
    float* sxx = (float*)(ws + (2u << 20));                        // 32 KB
    float* syy = (float*)(ws + (2u << 20) + 32768);                // 32 KB
    double* accum = (double*)(ws + (2u << 20) + 65536);            // 16 B

    mmd_prep<<<dim3(1024), dim3(256), 0, stream>>>(
        z_seq, pmean, pstd, z_prior, Xb, Yb, sxx, syy, accum);
    mmd_main<<<dim3(64, 64, 3), dim3(256), 0, stream>>>(
        Xb, Yb, sxx, syy, accum, out);
}

// Round 4
// 380.446 us; speedup vs baseline: 1.3156x; 1.3156x over previous
//
#include <hip/hip_runtime.h>
#include <hip/hip_bf16.h>

// ---------------------------------------------------------------------------
// MMD loss:  mmd = Sxx_up*2/(n(n-1)) + Syy_up*2/(m(m-1)) - 2*Sxy/(n*m)
// k(a,b) = exp(-|a-b|^2/128),  N = M = 8192, D = 64.
//
// k = exp2( (a.b)*C2L + nsa + nsb ) = exp2( fma(acc, C2L, nsa) ) * esb
//   nsa = -|a|^2*log2e/128  (A-side, log2 domain, precomputed)
//   esb = exp2(-|b|^2*log2e/128)  (B-side, exp2 domain, precomputed)
//
// Round-4 structure (r3 spilled: forced 8 waves/SIMD -> 131 MB scratch):
//  - NO LDS, NO forced launch bounds.  Block tile 32(i) x 512(j), 4 waves,
//    each 32x128.  All waves share A rows (L1-served); disjoint j -> B rows
//    hit L2 exactly once per block.
//  - A frags (16 VGPR) + nsa (8) persist; B strip + next-strip prefetch.
//  - epilogue 3 ops/elem: fma, exp2, fma.
//  - straddle-diagonal waves (rare) take a separate rolled guarded loop.
// ---------------------------------------------------------------------------

using short8 = __attribute__((ext_vector_type(8))) short;  // 8 bf16 (4 VGPRs)
using f32x4  = __attribute__((ext_vector_type(4))) float;  // 4 fp32

#define NROWS 8192
#define DDIM  64
#define LOG2E 1.4426950408889634f
#define TOTAL_BLOCKS (16 * 256 * 3)

// ---------------------------------------------------------------------------
// Prep: normalize X, cast X/Y to bf16; per row write ns = -|r|^2*log2e/128
// and es = exp2(ns).  16 threads/row, float4 each.  Block 0 zeroes accum.
// ---------------------------------------------------------------------------
__global__ __launch_bounds__(256) void mmd_prep(
    const float* __restrict__ z_seq, const float* __restrict__ pmean,
    const float* __restrict__ pstd, const float* __restrict__ z_prior,
    unsigned short* __restrict__ Xb, unsigned short* __restrict__ Yb,
    float* __restrict__ nsX, float* __restrict__ esX,
    float* __restrict__ nsY, float* __restrict__ esY,
    double* __restrict__ accum)
{
    if (blockIdx.x == 0 && threadIdx.x == 0) {
        accum[0] = 0.0;
        *reinterpret_cast<unsigned*>(accum + 1) = 0u;
    }
    const int gt  = blockIdx.x * 256 + threadIdx.x;  // 0..262143
    const int row = gt >> 4;                         // 0..16383
    const int sub = gt & 15;                         // 4 floats each

    float4 v;
    unsigned short* dst;
    float* nsd;
    float* esd;
    int r;
    if (row < NROWS) {
        r = row;
        v = *reinterpret_cast<const float4*>(z_seq + (size_t)r * DDIM + sub * 4);
        float4 m = *reinterpret_cast<const float4*>(pmean + sub * 4);
        float4 s = *reinterpret_cast<const float4*>(pstd + sub * 4);
        v.x = (v.x - m.x) / s.x;
        v.y = (v.y - m.y) / s.y;
        v.z = (v.z - m.z) / s.z;
        v.w = (v.w - m.w) / s.w;
        dst = Xb; nsd = nsX; esd = esX;
    } else {
        r = row - NROWS;
        v = *reinterpret_cast<const float4*>(z_prior + (size_t)r * DDIM + sub * 4);
        dst = Yb; nsd = nsY; esd = esY;
    }
    __hip_bfloat16 h0 = __float2bfloat16(v.x);
    __hip_bfloat16 h1 = __float2bfloat16(v.y);
    __hip_bfloat16 h2 = __float2bfloat16(v.z);
    __hip_bfloat16 h3 = __float2bfloat16(v.w);
    ushort4 pk;
    pk.x = *reinterpret_cast<unsigned short*>(&h0);
    pk.y = *reinterpret_cast<unsigned short*>(&h1);
    pk.z = *reinterpret_cast<unsigned short*>(&h2);
    pk.w = *reinterpret_cast<unsigned short*>(&h3);
    *reinterpret_cast<ushort4*>(dst + (size_t)r * DDIM + sub * 4) = pk;

    float b0 = __bfloat162float(h0), b1 = __bfloat162float(h1);
    float b2 = __bfloat162float(h2), b3 = __bfloat162float(h3);
    float sq = (b0 * b0 + b1 * b1) + (b2 * b2 + b3 * b3);
#pragma unroll
    for (int off = 1; off <= 8; off <<= 1) sq += __shfl_xor(sq, off, 64);
    if (sub == 0) {
        float ns = -sq * (LOG2E / 128.0f);
        nsd[r] = ns;
        esd[r] = __builtin_amdgcn_exp2f(ns);
    }
}

// ---------------------------------------------------------------------------
// Main: grid (16 bj, 256 bi, 3 modes).  Block tile 32(i) x 512(j).
// mode 0: XX (sym), 1: YY (sym), 2: XY.
// ---------------------------------------------------------------------------
__global__ __launch_bounds__(256) void mmd_main(
    const unsigned short* __restrict__ Xb, const unsigned short* __restrict__ Yb,
    const float* __restrict__ nsX, const float* __restrict__ esX,
    const float* __restrict__ nsY, const float* __restrict__ esY,
    double* __restrict__ accum, float* __restrict__ out)
{
    const int bj = blockIdx.x, bi = blockIdx.y, mode = blockIdx.z;
    const unsigned short* A;
    const unsigned short* Bp;
    const float* nsA;
    const float* esB;
    if (mode == 0)      { A = Xb; Bp = Xb; nsA = nsX; esB = esX; }
    else if (mode == 1) { A = Yb; Bp = Yb; nsA = nsY; esB = esY; }
    else                { A = Xb; Bp = Yb; nsA = nsX; esB = esY; }
    const bool sym = (mode < 2);

    const int t = threadIdx.x;
    const int lane = t & 63, w = t >> 6, quad = lane >> 4, l15 = lane & 15;
    const int i0 = bi * 32;
    const int j0 = bj * 512 + w * 128;

    constexpr float C2L = LOG2E / 64.0f;
    float s0 = 0.f, s1 = 0.f, s2 = 0.f, s3 = 0.f;

    const bool deadw = sym && (j0 + 128 <= i0);
    if (!deadw) {
        // ---- persistent A fragments + neg-norms (L1-served, shared by waves)
        const unsigned short* Ap = A + (size_t)(i0 + l15) * DDIM + quad * 8;
        short8 af[2][2];
        f32x4  nx[2];
#pragma unroll
        for (int mt = 0; mt < 2; ++mt) {
            af[mt][0] = *reinterpret_cast<const short8*>(Ap + mt * 16 * DDIM);
            af[mt][1] = *reinterpret_cast<const short8*>(Ap + mt * 16 * DDIM + 32);
            nx[mt]    = *reinterpret_cast<const f32x4*>(nsA + i0 + mt * 16 + quad * 4);
        }
        const unsigned short* Bl = Bp + (size_t)(j0 + l15) * DDIM + quad * 8;
        const float* eyp = esB + j0 + l15;

        if (!sym || j0 >= i0 + 32) {
            // ------------- clean wave: branch-free, next-strip prefetch ----
            short8 b0c = *reinterpret_cast<const short8*>(Bl);
            short8 b1c = *reinterpret_cast<const short8*>(Bl + 32);
            float  eyc = eyp[0];
#pragma unroll
            for (int nt = 0; nt < 8; ++nt) {
                short8 b0n, b1n; float eyn;
                if (nt < 7) {
                    b0n = *reinterpret_cast<const short8*>(Bl + (nt + 1) * 16 * DDIM);
                    b1n = *reinterpret_cast<const short8*>(Bl + (nt + 1) * 16 * DDIM + 32);
                    eyn = eyp[(nt + 1) * 16];
                }
#pragma unroll
                for (int mt = 0; mt < 2; ++mt) {
                    f32x4 a0 = {0.f, 0.f, 0.f, 0.f};
                    a0 = __builtin_amdgcn_mfma_f32_16x16x32_bf16(af[mt][0], b0c, a0, 0, 0, 0);
                    f32x4 acc = __builtin_amdgcn_mfma_f32_16x16x32_bf16(af[mt][1], b1c, a0, 0, 0, 0);
                    s0 = fmaf(__builtin_amdgcn_exp2f(fmaf(acc[0], C2L, nx[mt][0])), eyc, s0);
                    s1 = fmaf(__builtin_amdgcn_exp2f(fmaf(acc[1], C2L, nx[mt][1])), eyc, s1);
                    s2 = fmaf(__builtin_amdgcn_exp2f(fmaf(acc[2], C2L, nx[mt][2])), eyc, s2);
                    s3 = fmaf(__builtin_amdgcn_exp2f(fmaf(acc[3], C2L, nx[mt][3])), eyc, s3);
                }
                if (nt < 7) { b0c = b0n; b1c = b1n; eyc = eyn; }
            }
        } else {
            // ------------- diagonal-straddling wave (rare): rolled, guarded
#pragma unroll 1
            for (int nt = 0; nt < 8; ++nt) {
                const int jt = j0 + nt * 16;
                if (jt < i0) continue;             // below both sub-tiles
                short8 b0 = *reinterpret_cast<const short8*>(Bl + nt * 16 * DDIM);
                short8 b1 = *reinterpret_cast<const short8*>(Bl + nt * 16 * DDIM + 32);
                const float ey = eyp[nt * 16];
#pragma unroll
                for (int mt = 0; mt < 2; ++mt) {
                    const int it = i0 + mt * 16;
                    if (jt < it) continue;         // sub-tile below diagonal
                    f32x4 a0 = {0.f, 0.f, 0.f, 0.f};
                    a0 = __builtin_amdgcn_mfma_f32_16x16x32_bf16(af[mt][0], b0, a0, 0, 0, 0);
                    f32x4 acc = __builtin_amdgcn_mfma_f32_16x16x32_bf16(af[mt][1], b1, a0, 0, 0, 0);
                    if (jt == it) {                // strict upper triangle only
                        float m0 = (l15 > quad * 4 + 0) ? ey : 0.f;
                        float m1 = (l15 > quad * 4 + 1) ? ey : 0.f;
                        float m2 = (l15 > quad * 4 + 2) ? ey : 0.f;
                        float m3 = (l15 > quad * 4 + 3) ? ey : 0.f;
                        s0 = fmaf(__builtin_amdgcn_exp2f(fmaf(acc[0], C2L, nx[mt][0])), m0, s0);
                        s1 = fmaf(__builtin_amdgcn_exp2f(fmaf(acc[1], C2L, nx[mt][1])), m1, s1);
                        s2 = fmaf(__builtin_amdgcn_exp2f(fmaf(acc[2], C2L, nx[mt][2])), m2, s2);
                        s3 = fmaf(__builtin_amdgcn_exp2f(fmaf(acc[3], C2L, nx[mt][3])), m3, s3);
                    } else {
                        s0 = fmaf(__builtin_amdgcn_exp2f(fmaf(acc[0], C2L, nx[mt][0])), ey, s0);
                        s1 = fmaf(__builtin_amdgcn_exp2f(fmaf(acc[1], C2L, nx[mt][1])), ey, s1);
                        s2 = fmaf(__builtin_amdgcn_exp2f(fmaf(acc[2], C2L, nx[mt][2])), ey, s2);
                        s3 = fmaf(__builtin_amdgcn_exp2f(fmaf(acc[3], C2L, nx[mt][3])), ey, s3);
                    }
                }
            }
        }
    }

    // ---- block reduce + global accumulate (all blocks, incl. dead) ----
    float wsum = (s0 + s1) + (s2 + s3);
#pragma unroll
    for (int off = 32; off; off >>= 1) wsum += __shfl_xor(wsum, off, 64);

    __shared__ float ws4[4];
    if (lane == 0) ws4[w] = wsum;
    __syncthreads();
    if (t == 0) {
        const double coef = sym ? (2.0 / (8192.0 * 8191.0))
                                : (-2.0 / (8192.0 * 8192.0));
        atomicAdd(accum, (double)(ws4[0] + ws4[1] + ws4[2] + ws4[3]) * coef);
        __threadfence();
        unsigned tk = atomicAdd(reinterpret_cast<unsigned*>(accum + 1), 1u);
        if (tk == TOTAL_BLOCKS - 1) {
            double vsum = atomicAdd(accum, 0.0);   // device-scope read
            out[0] = (float)(vsum > 0.0 ? vsum : 0.0);
        }
    }
}

// ---------------------------------------------------------------------------
extern "C" void kernel_launch(void* const* d_in, const int* in_sizes, int n_in,
                              void* d_out, int out_size, void* d_ws, size_t ws_size,
                              hipStream_t stream) {
    const float* z_seq   = (const float*)d_in[0];   // [16,512,64]
    const float* pmean   = (const float*)d_in[1];   // [64]
    const float* pstd    = (const float*)d_in[2];   // [64]
    const float* z_prior = (const float*)d_in[3];   // [8192,64]
    float* out = (float*)d_out;

    char* ws = (char*)d_ws;
    unsigned short* Xb = (unsigned short*)(ws);                    // 1 MB
    unsigned short* Yb = (unsigned short*)(ws + (1u << 20));       // 1 MB
    float* nsX = (float*)(ws + (2u << 20));                        // 32 KB
    float* esX = (float*)(ws + (2u << 20) + 1 * 32768);            // 32 KB
    float* nsY = (float*)(ws + (2u << 20) + 2 * 32768);            // 32 KB
    float* esY = (float*)(ws + (2u << 20) + 3 * 32768);            // 32 KB
    double* accum = (double*)(ws + (2u << 20) + 4 * 32768);        // 16 B

    mmd_prep<<<dim3(1024), dim3(256), 0, stream>>>(
        z_seq, pmean, pstd, z_prior, Xb, Yb, nsX, esX, nsY, esY, accum);
    mmd_main<<<dim3(16, 256, 3), dim3(256), 0, stream>>>(
        Xb, Yb, nsX, esX, nsY, esY, accum, out);
}

// Round 5
// 212.779 us; speedup vs baseline: 2.3523x; 1.7880x over previous
//
#include <hip/hip_runtime.h>
#include <hip/hip_bf16.h>

// ---------------------------------------------------------------------------
// MMD loss:  mmd = Sxx_up*2/(n(n-1)) + Syy_up*2/(m(m-1)) - 2*Sxy/(n*m)
// k(a,b) = exp(-|a-b|^2/128),  N = M = 8192, D = 64.
//
// k = exp2( fma(a.b, C2L, nsa) ) * esb
//   nsa = -|a|^2*log2e/128  (A-side, log2 domain, precomputed)
//   esb = exp2(-|b|^2*log2e/128)  (B-side, exp2 domain, precomputed)
//
// Round-5 = round-1 geometry (proven 80 us) + three deltas:
//  - per-block float partial into array + ONE u32 ticket atomic (r2-r4's
//    same-cacheline f64 atomic + device fence per block was the 2-4x tail)
//  - ey-multiply epilogue (3 ops/elem; no fmin, no ny add)
//  - B strips loaded in pairs: 4 loads + 2 ey in flight -> 4 stall points
//    per wave instead of 8
// Block 128(i) x 256(j), wave 64x128, af[4][2] + nx[4] persistent, no LDS
// staging, no forced launch bounds.
// ---------------------------------------------------------------------------

using short8 = __attribute__((ext_vector_type(8))) short;  // 8 bf16 (4 VGPRs)
using f32x4  = __attribute__((ext_vector_type(4))) float;  // 4 fp32

#define NROWS 8192
#define DDIM  64
#define LOG2E 1.4426950408889634f
#define TOTAL_BLOCKS (32 * 64 * 3)

// ---------------------------------------------------------------------------
// Prep: normalize X, cast X/Y to bf16; per row write ns = -|r|^2*log2e/128
// and es = exp2(ns).  16 threads/row, float4 each.  Block 0 zeroes ticket.
// ---------------------------------------------------------------------------
__global__ __launch_bounds__(256) void mmd_prep(
    const float* __restrict__ z_seq, const float* __restrict__ pmean,
    const float* __restrict__ pstd, const float* __restrict__ z_prior,
    unsigned short* __restrict__ Xb, unsigned short* __restrict__ Yb,
    float* __restrict__ nsX, float* __restrict__ esX,
    float* __restrict__ nsY, float* __restrict__ esY,
    unsigned* __restrict__ ticket)
{
    if (blockIdx.x == 0 && threadIdx.x == 0) *ticket = 0u;

    const int gt  = blockIdx.x * 256 + threadIdx.x;  // 0..262143
    const int row = gt >> 4;                         // 0..16383
    const int sub = gt & 15;                         // 4 floats each

    float4 v;
    unsigned short* dst;
    float* nsd;
    float* esd;
    int r;
    if (row < NROWS) {
        r = row;
        v = *reinterpret_cast<const float4*>(z_seq + (size_t)r * DDIM + sub * 4);
        float4 m = *reinterpret_cast<const float4*>(pmean + sub * 4);
        float4 s = *reinterpret_cast<const float4*>(pstd + sub * 4);
        v.x = (v.x - m.x) / s.x;
        v.y = (v.y - m.y) / s.y;
        v.z = (v.z - m.z) / s.z;
        v.w = (v.w - m.w) / s.w;
        dst = Xb; nsd = nsX; esd = esX;
    } else {
        r = row - NROWS;
        v = *reinterpret_cast<const float4*>(z_prior + (size_t)r * DDIM + sub * 4);
        dst = Yb; nsd = nsY; esd = esY;
    }
    __hip_bfloat16 h0 = __float2bfloat16(v.x);
    __hip_bfloat16 h1 = __float2bfloat16(v.y);
    __hip_bfloat16 h2 = __float2bfloat16(v.z);
    __hip_bfloat16 h3 = __float2bfloat16(v.w);
    ushort4 pk;
    pk.x = *reinterpret_cast<unsigned short*>(&h0);
    pk.y = *reinterpret_cast<unsigned short*>(&h1);
    pk.z = *reinterpret_cast<unsigned short*>(&h2);
    pk.w = *reinterpret_cast<unsigned short*>(&h3);
    *reinterpret_cast<ushort4*>(dst + (size_t)r * DDIM + sub * 4) = pk;

    float b0 = __bfloat162float(h0), b1 = __bfloat162float(h1);
    float b2 = __bfloat162float(h2), b3 = __bfloat162float(h3);
    float sq = (b0 * b0 + b1 * b1) + (b2 * b2 + b3 * b3);
#pragma unroll
    for (int off = 1; off <= 8; off <<= 1) sq += __shfl_xor(sq, off, 64);
    if (sub == 0) {
        float ns = -sq * (LOG2E / 128.0f);
        nsd[r] = ns;
        esd[r] = __builtin_amdgcn_exp2f(ns);
    }
}

// ---------------------------------------------------------------------------
// Main: grid (32 bj, 64 bi, 3 modes).  Block 128(i) x 256(j), wave 64x128.
// Last-ticket block reduces the partials array and writes the output.
// ---------------------------------------------------------------------------
__global__ __launch_bounds__(256) void mmd_main(
    const unsigned short* __restrict__ Xb, const unsigned short* __restrict__ Yb,
    const float* __restrict__ nsX, const float* __restrict__ esX,
    const float* __restrict__ nsY, const float* __restrict__ esY,
    float* __restrict__ partials, unsigned* __restrict__ ticket,
    float* __restrict__ out)
{
    const int bj = blockIdx.x, bi = blockIdx.y, mode = blockIdx.z;
    const int bid = mode * 2048 + bi * 32 + bj;
    const unsigned short* A;
    const unsigned short* Bp;
    const float* nsA;
    const float* esB;
    if (mode == 0)      { A = Xb; Bp = Xb; nsA = nsX; esB = esX; }
    else if (mode == 1) { A = Yb; Bp = Yb; nsA = nsY; esB = esY; }
    else                { A = Xb; Bp = Yb; nsA = nsX; esB = esY; }
    const bool sym = (mode < 2);

    const int t = threadIdx.x;
    const int lane = t & 63, w = t >> 6, quad = lane >> 4, l15 = lane & 15;
    const int iBlock = bi * 128, jBlock = bj * 256;
    const int i0 = iBlock + (w >> 1) * 64;
    const int j0 = jBlock + (w & 1) * 128;

    constexpr float C2L = LOG2E / 64.0f;
    float s0 = 0.f, s1 = 0.f, s2 = 0.f, s3 = 0.f;

    const bool blockDead = sym && (jBlock + 256 <= iBlock);
    const bool waveDead  = sym && (j0 + 128 <= i0);
    if (!blockDead && !waveDead) {
        // ---- persistent A fragments + A-side neg-norms ----
        const unsigned short* Ap = A + (size_t)(i0 + l15) * DDIM + quad * 8;
        short8 af[4][2];
        f32x4  nx[4];
#pragma unroll
        for (int mt = 0; mt < 4; ++mt) {
            af[mt][0] = *reinterpret_cast<const short8*>(Ap + mt * 16 * DDIM);
            af[mt][1] = *reinterpret_cast<const short8*>(Ap + mt * 16 * DDIM + 32);
            nx[mt]    = *reinterpret_cast<const f32x4*>(nsA + i0 + mt * 16 + quad * 4);
        }
        const unsigned short* Bl = Bp + (size_t)(j0 + l15) * DDIM + quad * 8;
        const float* eyp = esB + j0 + l15;

        if (!sym || j0 >= i0 + 64) {
            // ------------- clean wave: strips in pairs, branch-free --------
#pragma unroll
            for (int np = 0; np < 4; ++np) {
                const unsigned short* p0 = Bl + (2 * np) * 16 * DDIM;
                const unsigned short* p1 = Bl + (2 * np + 1) * 16 * DDIM;
                short8 c0 = *reinterpret_cast<const short8*>(p0);
                short8 c1 = *reinterpret_cast<const short8*>(p0 + 32);
                short8 d0 = *reinterpret_cast<const short8*>(p1);
                short8 d1 = *reinterpret_cast<const short8*>(p1 + 32);
                float eyc = eyp[(2 * np) * 16];
                float eyd = eyp[(2 * np + 1) * 16];
#pragma unroll
                for (int mt = 0; mt < 4; ++mt) {
                    f32x4 a0 = {0.f, 0.f, 0.f, 0.f};
                    a0 = __builtin_amdgcn_mfma_f32_16x16x32_bf16(af[mt][0], c0, a0, 0, 0, 0);
                    f32x4 acc = __builtin_amdgcn_mfma_f32_16x16x32_bf16(af[mt][1], c1, a0, 0, 0, 0);
                    s0 = fmaf(__builtin_amdgcn_exp2f(fmaf(acc[0], C2L, nx[mt][0])), eyc, s0);
                    s1 = fmaf(__builtin_amdgcn_exp2f(fmaf(acc[1], C2L, nx[mt][1])), eyc, s1);
                    s2 = fmaf(__builtin_amdgcn_exp2f(fmaf(acc[2], C2L, nx[mt][2])), eyc, s2);
                    s3 = fmaf(__builtin_amdgcn_exp2f(fmaf(acc[3], C2L, nx[mt][3])), eyc, s3);
                }
#pragma unroll
                for (int mt = 0; mt < 4; ++mt) {
                    f32x4 a0 = {0.f, 0.f, 0.f, 0.f};
                    a0 = __builtin_amdgcn_mfma_f32_16x16x32_bf16(af[mt][0], d0, a0, 0, 0, 0);
                    f32x4 acc = __builtin_amdgcn_mfma_f32_16x16x32_bf16(af[mt][1], d1, a0, 0, 0, 0);
                    s0 = fmaf(__builtin_amdgcn_exp2f(fmaf(acc[0], C2L, nx[mt][0])), eyd, s0);
                    s1 = fmaf(__builtin_amdgcn_exp2f(fmaf(acc[1], C2L, nx[mt][1])), eyd, s1);
                    s2 = fmaf(__builtin_amdgcn_exp2f(fmaf(acc[2], C2L, nx[mt][2])), eyd, s2);
                    s3 = fmaf(__builtin_amdgcn_exp2f(fmaf(acc[3], C2L, nx[mt][3])), eyd, s3);
                }
            }
        } else {
            // ------------- diagonal-straddling wave (rare): rolled, guarded
#pragma unroll 1
            for (int nt = 0; nt < 8; ++nt) {
                const int jt = j0 + nt * 16;
                if (jt < i0) continue;             // below all sub-tiles
                const unsigned short* pp = Bl + nt * 16 * DDIM;
                short8 b0 = *reinterpret_cast<const short8*>(pp);
                short8 b1 = *reinterpret_cast<const short8*>(pp + 32);
                const float ey = eyp[nt * 16];
#pragma unroll
                for (int mt = 0; mt < 4; ++mt) {
                    const int it = i0 + mt * 16;
                    if (jt < it) continue;         // sub-tile below diagonal
                    f32x4 a0 = {0.f, 0.f, 0.f, 0.f};
                    a0 = __builtin_amdgcn_mfma_f32_16x16x32_bf16(af[mt][0], b0, a0, 0, 0, 0);
                    f32x4 acc = __builtin_amdgcn_mfma_f32_16x16x32_bf16(af[mt][1], b1, a0, 0, 0, 0);
                    if (jt == it) {                // strict upper triangle only
                        float m0 = (l15 > quad * 4 + 0) ? ey : 0.f;
                        float m1 = (l15 > quad * 4 + 1) ? ey : 0.f;
                        float m2 = (l15 > quad * 4 + 2) ? ey : 0.f;
                        float m3 = (l15 > quad * 4 + 3) ? ey : 0.f;
                        s0 = fmaf(__builtin_amdgcn_exp2f(fmaf(acc[0], C2L, nx[mt][0])), m0, s0);
                        s1 = fmaf(__builtin_amdgcn_exp2f(fmaf(acc[1], C2L, nx[mt][1])), m1, s1);
                        s2 = fmaf(__builtin_amdgcn_exp2f(fmaf(acc[2], C2L, nx[mt][2])), m2, s2);
                        s3 = fmaf(__builtin_amdgcn_exp2f(fmaf(acc[3], C2L, nx[mt][3])), m3, s3);
                    } else {
                        s0 = fmaf(__builtin_amdgcn_exp2f(fmaf(acc[0], C2L, nx[mt][0])), ey, s0);
                        s1 = fmaf(__builtin_amdgcn_exp2f(fmaf(acc[1], C2L, nx[mt][1])), ey, s1);
                        s2 = fmaf(__builtin_amdgcn_exp2f(fmaf(acc[2], C2L, nx[mt][2])), ey, s2);
                        s3 = fmaf(__builtin_amdgcn_exp2f(fmaf(acc[3], C2L, nx[mt][3])), ey, s3);
                    }
                }
            }
        }
    }

    // ---- block reduce, store partial, ticket; last block finalizes ----
    float wsum = (s0 + s1) + (s2 + s3);
#pragma unroll
    for (int off = 32; off; off >>= 1) wsum += __shfl_xor(wsum, off, 64);

    __shared__ float ws4[4];
    __shared__ int lastFlag;
    if (lane == 0) ws4[w] = wsum;
    __syncthreads();
    if (t == 0) {
        partials[bid] = (ws4[0] + ws4[1]) + (ws4[2] + ws4[3]);
        __threadfence();
        unsigned tk = atomicAdd(ticket, 1u);
        lastFlag = (tk == TOTAL_BLOCKS - 1) ? 1 : 0;
    }
    __syncthreads();

    if (lastFlag) {
        const double cs = 2.0 / (8192.0 * 8191.0);    // modes 0,1 (upper tri x2)
        const double cx = -2.0 / (8192.0 * 8192.0);   // mode 2
        double s = 0.0;
        for (int i = t; i < TOTAL_BLOCKS; i += 256) {
            float p = atomicAdd(&partials[i], 0.0f);  // coherent device read
            s += (double)p * ((i < 4096) ? cs : cx);
        }
#pragma unroll
        for (int off = 32; off; off >>= 1) s += __shfl_xor(s, off, 64);
        __shared__ double wd[4];
        if (lane == 0) wd[w] = s;
        __syncthreads();
        if (t == 0) {
            double v = (wd[0] + wd[1]) + (wd[2] + wd[3]);
            out[0] = (float)(v > 0.0 ? v : 0.0);
        }
    }
}

// ---------------------------------------------------------------------------
extern "C" void kernel_launch(void* const* d_in, const int* in_sizes, int n_in,
                              void* d_out, int out_size, void* d_ws, size_t ws_size,
                              hipStream_t stream) {
    const float* z_seq   = (const float*)d_in[0];   // [16,512,64]
    const float* pmean   = (const float*)d_in[1];   // [64]
    const float* pstd    = (const float*)d_in[2];   // [64]
    const float* z_prior = (const float*)d_in[3];   // [8192,64]
    float* out = (float*)d_out;

    char* ws = (char*)d_ws;
    unsigned short* Xb = (unsigned short*)(ws);                    // 1 MB
    unsigned short* Yb = (unsigned short*)(ws + (1u << 20));       // 1 MB
    float* nsX = (float*)(ws + (2u << 20));                        // 32 KB
    float* esX = (float*)(ws + (2u << 20) + 1 * 32768);            // 32 KB
    float* nsY = (float*)(ws + (2u << 20) + 2 * 32768);            // 32 KB
    float* esY = (float*)(ws + (2u << 20) + 3 * 32768);            // 32 KB
    float* partials = (float*)(ws + (2u << 20) + 4 * 32768);       // 24 KB
    unsigned* ticket = (unsigned*)(ws + (2u << 20) + 4 * 32768 + 24576);

    mmd_prep<<<dim3(1024), dim3(256), 0, stream>>>(
        z_seq, pmean, pstd, z_prior, Xb, Yb, nsX, esX, nsY, esY, ticket);
    mmd_main<<<dim3(32, 64, 3), dim3(256), 0, stream>>>(
        Xb, Yb, nsX, esX, nsY, esY, partials, ticket, out);
}

// Round 6
// 142.169 us; speedup vs baseline: 3.5207x; 1.4967x over previous
//
#include <hip/hip_runtime.h>
#include <hip/hip_bf16.h>

// ---------------------------------------------------------------------------
// MMD loss:  mmd = Sxx_up*2/(n(n-1)) + Syy_up*2/(m(m-1)) - 2*Sxy/(n*m)
// k(a,b) = exp(-|a-b|^2/128),  N = M = 8192, D = 64.
//
// k = exp2( fma(a.b, C2L, nsa) ) * esb
//   nsa = -|a|^2*log2e/128  (A-side, log2 domain, precomputed)
//   esb = exp2(-|b|^2*log2e/128) (B-side, exp2 domain, precomputed)
//
// Round-6: residency-first restructure.
//  - 1024-thread blocks (16 waves, 4x4), block tile 256(i) x 512(j):
//    one resident block = 4 waves/SIMD (2x r5's measured 1.75), two = 100%.
//  - live-only 1-D grid (1056 blocks): XX upper-tri 272 + YY 272 + XY 512;
//    closed-form unrank, no dead-block dispatch churn.
//  - inner loop = r1's proven per-strip form (44 VGPR) + ey epilogue.
//  - per-block float partial + one u32 ticket atomic; last block reduces.
// ---------------------------------------------------------------------------

using short8 = __attribute__((ext_vector_type(8))) short;  // 8 bf16 (4 VGPRs)
using f32x4  = __attribute__((ext_vector_type(4))) float;  // 4 fp32

#define NROWS 8192
#define DDIM  64
#define LOG2E 1.4426950408889634f
#define NBLK_SYM 272                 // 256-row x 512-col upper-tri tiles
#define NBLK_TOT 1056                // 272 + 272 + 512

// ---------------------------------------------------------------------------
// Prep: normalize X, cast X/Y to bf16; per row write ns = -|r|^2*log2e/128
// and es = exp2(ns).  16 threads/row, float4 each.  Block 0 zeroes ticket.
// ---------------------------------------------------------------------------
__global__ __launch_bounds__(256) void mmd_prep(
    const float* __restrict__ z_seq, const float* __restrict__ pmean,
    const float* __restrict__ pstd, const float* __restrict__ z_prior,
    unsigned short* __restrict__ Xb, unsigned short* __restrict__ Yb,
    float* __restrict__ nsX, float* __restrict__ esX,
    float* __restrict__ nsY, float* __restrict__ esY,
    unsigned* __restrict__ ticket)
{
    if (blockIdx.x == 0 && threadIdx.x == 0) *ticket = 0u;

    const int gt  = blockIdx.x * 256 + threadIdx.x;  // 0..262143
    const int row = gt >> 4;                         // 0..16383
    const int sub = gt & 15;                         // 4 floats each

    float4 v;
    unsigned short* dst;
    float* nsd;
    float* esd;
    int r;
    if (row < NROWS) {
        r = row;
        v = *reinterpret_cast<const float4*>(z_seq + (size_t)r * DDIM + sub * 4);
        float4 m = *reinterpret_cast<const float4*>(pmean + sub * 4);
        float4 s = *reinterpret_cast<const float4*>(pstd + sub * 4);
        v.x = (v.x - m.x) / s.x;
        v.y = (v.y - m.y) / s.y;
        v.z = (v.z - m.z) / s.z;
        v.w = (v.w - m.w) / s.w;
        dst = Xb; nsd = nsX; esd = esX;
    } else {
        r = row - NROWS;
        v = *reinterpret_cast<const float4*>(z_prior + (size_t)r * DDIM + sub * 4);
        dst = Yb; nsd = nsY; esd = esY;
    }
    __hip_bfloat16 h0 = __float2bfloat16(v.x);
    __hip_bfloat16 h1 = __float2bfloat16(v.y);
    __hip_bfloat16 h2 = __float2bfloat16(v.z);
    __hip_bfloat16 h3 = __float2bfloat16(v.w);
    ushort4 pk;
    pk.x = *reinterpret_cast<unsigned short*>(&h0);
    pk.y = *reinterpret_cast<unsigned short*>(&h1);
    pk.z = *reinterpret_cast<unsigned short*>(&h2);
    pk.w = *reinterpret_cast<unsigned short*>(&h3);
    *reinterpret_cast<ushort4*>(dst + (size_t)r * DDIM + sub * 4) = pk;

    float b0 = __bfloat162float(h0), b1 = __bfloat162float(h1);
    float b2 = __bfloat162float(h2), b3 = __bfloat162float(h3);
    float sq = (b0 * b0 + b1 * b1) + (b2 * b2 + b3 * b3);
#pragma unroll
    for (int off = 1; off <= 8; off <<= 1) sq += __shfl_xor(sq, off, 64);
    if (sub == 0) {
        float ns = -sq * (LOG2E / 128.0f);
        nsd[r] = ns;
        esd[r] = __builtin_amdgcn_exp2f(ns);
    }
}

// ---------------------------------------------------------------------------
// Main: 1-D grid of 1056 live blocks.  1024 threads = 16 waves (4x4),
// block tile 256(i) x 512(j), wave tile 64 x 128.
// ---------------------------------------------------------------------------
__global__ __launch_bounds__(1024) void mmd_main(
    const unsigned short* __restrict__ Xb, const unsigned short* __restrict__ Yb,
    const float* __restrict__ nsX, const float* __restrict__ esX,
    const float* __restrict__ nsY, const float* __restrict__ esY,
    float* __restrict__ partials, unsigned* __restrict__ ticket,
    float* __restrict__ out)
{
    const int blk = blockIdx.x;

    // ---- unrank linear block id -> (mode, bi, bj) over live tiles only ----
    int mode, bi, bj;
    if (blk < 2 * NBLK_SYM) {
        mode = (blk < NBLK_SYM) ? 0 : 1;
        const int l = blk - mode * NBLK_SYM;       // 0..271
        // largest b with b^2+b <= l   (per-bj live count = 2bj+2)
        int b = (int)((__builtin_sqrtf((float)(4 * l + 1)) - 1.0f) * 0.5f);
        while (b > 0 && b * b + b > l) --b;
        while ((b + 1) * (b + 1) + (b + 1) <= l) ++b;
        bj = b;
        bi = l - (b * b + b);                      // 0 .. 2bj+1
    } else {
        mode = 2;
        const int q = blk - 2 * NBLK_SYM;          // 0..511
        bi = q >> 4;                               // 0..31
        bj = q & 15;                               // 0..15
    }

    const unsigned short* A;
    const unsigned short* Bp;
    const float* nsA;
    const float* esB;
    if (mode == 0)      { A = Xb; Bp = Xb; nsA = nsX; esB = esX; }
    else if (mode == 1) { A = Yb; Bp = Yb; nsA = nsY; esB = esY; }
    else                { A = Xb; Bp = Yb; nsA = nsX; esB = esY; }
    const bool sym = (mode < 2);

    const int t = threadIdx.x;
    const int lane = t & 63, w = t >> 6, quad = lane >> 4, l15 = lane & 15;
    const int i0 = bi * 256 + (w >> 2) * 64;       // wave row origin
    const int j0 = bj * 512 + (w & 3) * 128;       // wave col origin

    constexpr float C2L = LOG2E / 64.0f;
    float s0 = 0.f, s1 = 0.f, s2 = 0.f, s3 = 0.f;

    const bool waveDead = sym && (j0 + 128 <= i0);
    if (!waveDead) {
        // ---- persistent A fragments + A-side neg-norms ----
        const unsigned short* Ap = A + (size_t)(i0 + l15) * DDIM + quad * 8;
        short8 af[4][2];
        f32x4  nx[4];
#pragma unroll
        for (int mt = 0; mt < 4; ++mt) {
            af[mt][0] = *reinterpret_cast<const short8*>(Ap + mt * 16 * DDIM);
            af[mt][1] = *reinterpret_cast<const short8*>(Ap + mt * 16 * DDIM + 32);
            nx[mt]    = *reinterpret_cast<const f32x4*>(nsA + i0 + mt * 16 + quad * 4);
        }
        const unsigned short* Bl = Bp + (size_t)(j0 + l15) * DDIM + quad * 8;
        const float* eyp = esB + j0 + l15;

        if (!sym || j0 >= i0 + 64) {
            // ------------- clean wave: r1's proven per-strip loop ----------
#pragma unroll
            for (int nt = 0; nt < 8; ++nt) {
                const float ey = eyp[nt * 16];
                const unsigned short* pp = Bl + nt * 16 * DDIM;
                short8 b0 = *reinterpret_cast<const short8*>(pp);
                short8 b1 = *reinterpret_cast<const short8*>(pp + 32);
#pragma unroll
                for (int mt = 0; mt < 4; ++mt) {
                    f32x4 a0 = {0.f, 0.f, 0.f, 0.f};
                    a0 = __builtin_amdgcn_mfma_f32_16x16x32_bf16(af[mt][0], b0, a0, 0, 0, 0);
                    f32x4 acc = __builtin_amdgcn_mfma_f32_16x16x32_bf16(af[mt][1], b1, a0, 0, 0, 0);
                    s0 = fmaf(__builtin_amdgcn_exp2f(fmaf(acc[0], C2L, nx[mt][0])), ey, s0);
                    s1 = fmaf(__builtin_amdgcn_exp2f(fmaf(acc[1], C2L, nx[mt][1])), ey, s1);
                    s2 = fmaf(__builtin_amdgcn_exp2f(fmaf(acc[2], C2L, nx[mt][2])), ey, s2);
                    s3 = fmaf(__builtin_amdgcn_exp2f(fmaf(acc[3], C2L, nx[mt][3])), ey, s3);
                }
            }
        } else {
            // ------------- diagonal-straddling wave (rare): rolled, guarded
#pragma unroll 1
            for (int nt = 0; nt < 8; ++nt) {
                const int jt = j0 + nt * 16;
                if (jt < i0) continue;             // below all sub-tiles
                const unsigned short* pp = Bl + nt * 16 * DDIM;
                short8 b0 = *reinterpret_cast<const short8*>(pp);
                short8 b1 = *reinterpret_cast<const short8*>(pp + 32);
                const float ey = eyp[nt * 16];
#pragma unroll
                for (int mt = 0; mt < 4; ++mt) {
                    const int it = i0 + mt * 16;
                    if (jt < it) continue;         // sub-tile below diagonal
                    f32x4 a0 = {0.f, 0.f, 0.f, 0.f};
                    a0 = __builtin_amdgcn_mfma_f32_16x16x32_bf16(af[mt][0], b0, a0, 0, 0, 0);
                    f32x4 acc = __builtin_amdgcn_mfma_f32_16x16x32_bf16(af[mt][1], b1, a0, 0, 0, 0);
                    if (jt == it) {                // strict upper triangle only
                        float m0 = (l15 > quad * 4 + 0) ? ey : 0.f;
                        float m1 = (l15 > quad * 4 + 1) ? ey : 0.f;
                        float m2 = (l15 > quad * 4 + 2) ? ey : 0.f;
                        float m3 = (l15 > quad * 4 + 3) ? ey : 0.f;
                        s0 = fmaf(__builtin_amdgcn_exp2f(fmaf(acc[0], C2L, nx[mt][0])), m0, s0);
                        s1 = fmaf(__builtin_amdgcn_exp2f(fmaf(acc[1], C2L, nx[mt][1])), m1, s1);
                        s2 = fmaf(__builtin_amdgcn_exp2f(fmaf(acc[2], C2L, nx[mt][2])), m2, s2);
                        s3 = fmaf(__builtin_amdgcn_exp2f(fmaf(acc[3], C2L, nx[mt][3])), m3, s3);
                    } else {
                        s0 = fmaf(__builtin_amdgcn_exp2f(fmaf(acc[0], C2L, nx[mt][0])), ey, s0);
                        s1 = fmaf(__builtin_amdgcn_exp2f(fmaf(acc[1], C2L, nx[mt][1])), ey, s1);
                        s2 = fmaf(__builtin_amdgcn_exp2f(fmaf(acc[2], C2L, nx[mt][2])), ey, s2);
                        s3 = fmaf(__builtin_amdgcn_exp2f(fmaf(acc[3], C2L, nx[mt][3])), ey, s3);
                    }
                }
            }
        }
    }

    // ---- block reduce (16 waves), store partial, ticket; last finalizes ----
    float wsum = (s0 + s1) + (s2 + s3);
#pragma unroll
    for (int off = 32; off; off >>= 1) wsum += __shfl_xor(wsum, off, 64);

    __shared__ float ws16[16];
    __shared__ int lastFlag;
    if (lane == 0) ws16[w] = wsum;
    __syncthreads();
    if (t == 0) {
        float tot = 0.f;
#pragma unroll
        for (int k = 0; k < 16; ++k) tot += ws16[k];
        partials[blk] = tot;
        __threadfence();
        unsigned tk = atomicAdd(ticket, 1u);
        lastFlag = (tk == NBLK_TOT - 1) ? 1 : 0;
    }
    __syncthreads();

    if (lastFlag) {
        const double cs = 2.0 / (8192.0 * 8191.0);    // sym modes (upper tri x2)
        const double cx = -2.0 / (8192.0 * 8192.0);   // XY mode
        double s = 0.0;
        for (int i = t; i < NBLK_TOT; i += 1024) {
            float p = atomicAdd(&partials[i], 0.0f);  // coherent device read
            s += (double)p * ((i < 2 * NBLK_SYM) ? cs : cx);
        }
#pragma unroll
        for (int off = 32; off; off >>= 1) s += __shfl_xor(s, off, 64);
        __shared__ double wd[16];
        if (lane == 0) wd[w] = s;
        __syncthreads();
        if (t == 0) {
            double v = 0.0;
#pragma unroll
            for (int k = 0; k < 16; ++k) v += wd[k];
            out[0] = (float)(v > 0.0 ? v : 0.0);
        }
    }
}

// ---------------------------------------------------------------------------
extern "C" void kernel_launch(void* const* d_in, const int* in_sizes, int n_in,
                              void* d_out, int out_size, void* d_ws, size_t ws_size,
                              hipStream_t stream) {
    const float* z_seq   = (const float*)d_in[0];   // [16,512,64]
    const float* pmean   = (const float*)d_in[1];   // [64]
    const float* pstd    = (const float*)d_in[2];   // [64]
    const float* z_prior = (const float*)d_in[3];   // [8192,64]
    float* out = (float*)d_out;

    char* ws = (char*)d_ws;
    unsigned short* Xb = (unsigned short*)(ws);                    // 1 MB
    unsigned short* Yb = (unsigned short*)(ws + (1u << 20));       // 1 MB
    float* nsX = (float*)(ws + (2u << 20));                        // 32 KB
    float* esX = (float*)(ws + (2u << 20) + 1 * 32768);            // 32 KB
    float* nsY = (float*)(ws + (2u << 20) + 2 * 32768);            // 32 KB
    float* esY = (float*)(ws + (2u << 20) + 3 * 32768);            // 32 KB
    float* partials = (float*)(ws + (2u << 20) + 4 * 32768);       // ~4.2 KB
    unsigned* ticket = (unsigned*)(ws + (2u << 20) + 4 * 32768 + 8192);

    mmd_prep<<<dim3(1024), dim3(256), 0, stream>>>(
        z_seq, pmean, pstd, z_prior, Xb, Yb, nsX, esX, nsY, esY, ticket);
    mmd_main<<<dim3(NBLK_TOT), dim3(1024), 0, stream>>>(
        Xb, Yb, nsX, esX, nsY, esY, partials, ticket, out);
}